// Round 4
// baseline (383.209 us; speedup 1.0000x reference)
//
#include <hip/hip_runtime.h>
#include <hip/hip_bf16.h>

constexpr int Bb = 4;      // batch
constexpr int Tt = 1024;   // tokens
constexpr int Cc = 1024;   // channels
constexpr int HD = 64;     // head dim
constexpr int Kk = 16;     // sparse K

// fp32 VALU LDS-tiled GEMM: C[M,N] = A[M,K] @ B[N,K]^T.
// GATHER: A row m comes from x row (m>>4)*Tt + (m&15) (first 16 tokens per batch).
// Block = 256 threads -> 64x64 C tile; each thread computes 4x4. K-step = 32.
template<bool GATHER>
__global__ __launch_bounds__(256)
void gemm_valu(const float* __restrict__ A, const float* __restrict__ Bm,
               float* __restrict__ Cout, int M, int N, int K)
{
    __shared__ float As[32][68];   // [k][m], pad 68 keeps 16B alignment, kills conflicts
    __shared__ float Bs[32][68];   // [k][n]
    const int tid = threadIdx.x;
    const int tx = tid & 15, ty = tid >> 4;
    const int tileM = blockIdx.y * 64;
    const int tileN = blockIdx.x * 64;

    float acc[4][4] = {};
    for (int kk = 0; kk < K; kk += 32) {
#pragma unroll
        for (int i = 0; i < 2; ++i) {
            int lin = tid + i * 256;       // 0..511
            int row = lin >> 3;            // 0..63 (m or n within tile)
            int c4  = (lin & 7) * 4;       // k offset within 32: 0,4,..,28
            int am = tileM + row;
            size_t arow = GATHER ? ((size_t)(am >> 4) * Tt + (am & 15)) : (size_t)am;
            float4 av = *reinterpret_cast<const float4*>(A + arow * (size_t)K + kk + c4);
            As[c4 + 0][row] = av.x; As[c4 + 1][row] = av.y;
            As[c4 + 2][row] = av.z; As[c4 + 3][row] = av.w;
            float4 bv = *reinterpret_cast<const float4*>(
                Bm + (size_t)(tileN + row) * K + kk + c4);
            Bs[c4 + 0][row] = bv.x; Bs[c4 + 1][row] = bv.y;
            Bs[c4 + 2][row] = bv.z; Bs[c4 + 3][row] = bv.w;
        }
        __syncthreads();
#pragma unroll
        for (int k2 = 0; k2 < 32; ++k2) {
            float4 a = *reinterpret_cast<const float4*>(&As[k2][ty * 4]);
            float4 b = *reinterpret_cast<const float4*>(&Bs[k2][tx * 4]);
            const float av[4] = {a.x, a.y, a.z, a.w};
            const float bv[4] = {b.x, b.y, b.z, b.w};
#pragma unroll
            for (int i = 0; i < 4; ++i)
#pragma unroll
                for (int j = 0; j < 4; ++j)
                    acc[i][j] += av[i] * bv[j];
        }
        __syncthreads();
    }

#pragma unroll
    for (int i = 0; i < 4; ++i)
#pragma unroll
        for (int j = 0; j < 4; ++j) {
            size_t row = tileM + ty * 4 + i;
            size_t col = tileN + tx * 4 + j;
            Cout[row * N + col] = acc[i][j];
        }
}

// One thread per (b,h,t). Block of 256 covers 256 consecutive t for one (b,h).
// kv: fp32 [Bb*16][2*Cc] (cols 0..1023 = K channels, 1024..2047 = V channels).
// Fixed key set = tokens 0..15 (degenerate top-k), validity mask slot <= t.
__global__ __launch_bounds__(256)
void attn_kernel(const float* __restrict__ q,    // [Bb*Tt][Cc] fp32
                 const float* __restrict__ kv,
                 float* __restrict__ attn)        // [Bb*Tt][Cc] fp32
{
    __shared__ float ks[Kk][HD];
    __shared__ float vs[Kk][HD];
    const int bid = blockIdx.x;       // (b*16 + h)*4 + tchunk
    const int bh = bid >> 2;
    const int tchunk = bid & 3;
    const int b = bh >> 4;
    const int h = bh & 15;

    for (int e = threadIdx.x; e < Kk * HD; e += 256) {
        int slot = e >> 6, d = e & 63;
        size_t rowoff = (size_t)(b * Kk + slot) * (2 * Cc);
        ks[slot][d] = kv[rowoff + h * HD + d];
        vs[slot][d] = kv[rowoff + Cc + h * HD + d];
    }
    __syncthreads();

    const int t = tchunk * 256 + threadIdx.x;
    const size_t m = (size_t)b * Tt + t;

    float qf[HD];
    const float* qrow = q + m * Cc + (size_t)h * HD;
#pragma unroll
    for (int d = 0; d < HD; d += 4) {
        float4 v = *reinterpret_cast<const float4*>(qrow + d);
        qf[d] = v.x; qf[d + 1] = v.y; qf[d + 2] = v.z; qf[d + 3] = v.w;
    }

    const int nv = min(t, Kk - 1) + 1;   // valid slots: slot <= t
    float logits[Kk];
    float mx = -3.0e38f;
    for (int k = 0; k < Kk; ++k) {
        float s = 0.f;
#pragma unroll
        for (int d = 0; d < HD; ++d) s += qf[d] * ks[k][d];
        s *= 0.125f;                      // 1/sqrt(64)
        logits[k] = s;
        if (k < nv) mx = fmaxf(mx, s);
    }
    float w[Kk];
    float sum = 0.f;
    for (int k = 0; k < Kk; ++k) {
        float e = (k < nv) ? __expf(logits[k] - mx) : 0.f;
        w[k] = e;
        sum += e;
    }
    const float inv = 1.f / sum;

    float outv[HD];
#pragma unroll
    for (int d = 0; d < HD; ++d) outv[d] = 0.f;
    for (int k = 0; k < nv; ++k) {
        float wk = w[k] * inv;
#pragma unroll
        for (int d = 0; d < HD; ++d) outv[d] += wk * vs[k][d];
    }

    float* orow = attn + m * Cc + (size_t)h * HD;
#pragma unroll
    for (int d = 0; d < HD; ++d) orow[d] = outv[d];
}

extern "C" void kernel_launch(void* const* d_in, const int* in_sizes, int n_in,
                              void* d_out, int out_size, void* d_ws, size_t ws_size,
                              hipStream_t stream)
{
    (void)in_sizes; (void)n_in; (void)out_size; (void)ws_size;
    const float* x      = (const float*)d_in[0];
    const float* W_attn = (const float*)d_in[1];
    const float* W_proj = (const float*)d_in[2];
    // d_in[3] = W_rel is dead under the degenerate-top-k reading: top_k values
    // are discarded; scores[h,t,:] has its only finite entry at j=0, ties at
    // -inf break to ascending indices (JAX top_k is stable) -> idx = [0..15].
    float* out = (float*)d_out;   // ROUND-4 EXPERIMENT: fp32 output store

    char* ws = (char*)d_ws;
    float* kv_ws   = (float*)ws;                                  // 64*2048*4   = 512 KB
    float* q_ws    = (float*)(ws + (512u << 10));                 // 4096*1024*4 = 16 MB
    float* attn_ws = (float*)(ws + (512u << 10) + (16u << 20));   // 16 MB

    // K/V for tokens 0..15 of each batch: M=64 (gathered rows), N=2048 (Wk|Wv), K=1024.
    gemm_valu<true><<<dim3(2048 / 64, 1), 256, 0, stream>>>(
        x, W_attn + (size_t)Cc * Cc, kv_ws, 64, 2048, Cc);
    // Q: M=4096, N=1024, K=1024 (fp32 out).
    gemm_valu<false><<<dim3(Cc / 64, (Bb * Tt) / 64), 256, 0, stream>>>(
        x, W_attn, q_ws, Bb * Tt, Cc, Cc);
    // Sparse attention (fixed 16 keys, validity slot<=t), fp32.
    attn_kernel<<<Bb * 16 * (Tt / 256), 256, 0, stream>>>(q_ws, kv_ws, attn_ws);
    // Output projection -> d_out, fp32.
    gemm_valu<false><<<dim3(Cc / 64, (Bb * Tt) / 64), 256, 0, stream>>>(
        attn_ws, W_proj, out, Bb * Tt, Cc, Cc);
}

// Round 5
// 159.106 us; speedup vs baseline: 2.4085x; 2.4085x over previous
//
#include <hip/hip_runtime.h>
#include <hip/hip_bf16.h>
#include <stdint.h>

typedef __bf16 bf16x8 __attribute__((ext_vector_type(8)));
typedef float  f32x4  __attribute__((ext_vector_type(4)));

constexpr int Bb = 4;      // batch
constexpr int Tt = 1024;   // tokens
constexpr int Cc = 1024;   // channels
constexpr int HD = 64;     // head dim
constexpr int Kk = 16;     // sparse K

__device__ inline __bf16 f2bf(float f) {
    union { __hip_bfloat16 h; __bf16 b; } u;
    u.h = __float2bfloat16(f);
    return u.b;
}

// Async global->LDS, 16B per lane. LDS dest is wave-uniform base + lane*16
// (m104 caveat). AS casts per composable_kernel's production pattern.
__device__ inline void load_lds16(const __hip_bfloat16* g, __hip_bfloat16* l) {
    auto gp = (const __attribute__((address_space(1))) unsigned int*)(uintptr_t)g;
    auto lp = (__attribute__((address_space(3))) unsigned int*)(uintptr_t)l;
    __builtin_amdgcn_global_load_lds(gp, lp, 16, 0, 0);
}

__global__ __launch_bounds__(256)
void cvt_f32_bf16(const float* __restrict__ src, __hip_bfloat16* __restrict__ dst, int n)
{
    int i = (blockIdx.x * 256 + threadIdx.x) * 8;
    if (i >= n) return;
    float4 a = *reinterpret_cast<const float4*>(src + i);
    float4 b = *reinterpret_cast<const float4*>(src + i + 4);
    bf16x8 v;
    v[0] = f2bf(a.x); v[1] = f2bf(a.y); v[2] = f2bf(a.z); v[3] = f2bf(a.w);
    v[4] = f2bf(b.x); v[5] = f2bf(b.y); v[6] = f2bf(b.z); v[7] = f2bf(b.w);
    *reinterpret_cast<bf16x8*>(dst + i) = v;
}

// C[M,N] = A[M,K] @ B[N,K]^T, A/B bf16 row-major, fp32 accum.
// Block = 256 threads (4 waves, 2x2); wave tile (BM/2)x(BN/2); frags 16x16x32.
// LDS staged via global_load_lds width-16; BK=32; 2-barrier K-loop (m97 shape).
// GATHER: A row m comes from row (m>>4)*Tt + (m&15) (first 16 tokens per batch).
template<int BM, int BN, bool GATHER, bool OUT_BF16>
__global__ __launch_bounds__(256)
void gemm_mfma(const __hip_bfloat16* __restrict__ A,
               const __hip_bfloat16* __restrict__ Bm,
               void* __restrict__ Cout, int M, int N, int K)
{
    constexpr int FI = BM / 32;          // A frags per wave
    constexpr int FJ = BN / 32;          // B frags per wave
    __shared__ __hip_bfloat16 smem[(BM + BN) * 32];
    __hip_bfloat16* As = smem;           // [BM][32] row-major
    __hip_bfloat16* Bs = smem + BM * 32; // [BN][32]

    const int lane = threadIdx.x & 63;
    const int wave = threadIdx.x >> 6;
    const int wm = wave >> 1, wn = wave & 1;
    const int tileM = blockIdx.y * BM;
    const int tileN = blockIdx.x * BN;
    const int r16 = lane & 15;
    const int kq  = (lane >> 4) * 8;

    f32x4 acc[FI][FJ] = {};

    for (int kk = 0; kk < K; kk += 32) {
        // Stage A tile: BM*64 bytes, 16B chunks; chunk g covers row g>>2, cols (g&3)*8..+7.
#pragma unroll
        for (int t = 0; t < BM / 64; ++t) {
            int g = (wave * (BM / 64) + t) * 64 + lane;
            int r = g >> 2;
            int col = (g & 3) * 8;
            int am = tileM + r;
            size_t grow = GATHER ? ((size_t)(am >> 4) * Tt + (am & 15)) : (size_t)am;
            load_lds16(A + grow * (size_t)K + kk + col,
                       As + (size_t)(wave * (BM / 64) + t) * 512);
        }
#pragma unroll
        for (int t = 0; t < BN / 64; ++t) {
            int g = (wave * (BN / 64) + t) * 64 + lane;
            int r = g >> 2;
            int col = (g & 3) * 8;
            load_lds16(Bm + (size_t)(tileN + r) * K + kk + col,
                       Bs + (size_t)(wave * (BN / 64) + t) * 512);
        }
        __syncthreads();   // compiler emits vmcnt(0) drain before barrier

        bf16x8 a[FI], b[FJ];
#pragma unroll
        for (int i = 0; i < FI; ++i)
            a[i] = *reinterpret_cast<const bf16x8*>(
                As + (size_t)(wm * (BM / 2) + i * 16 + r16) * 32 + kq);
#pragma unroll
        for (int j = 0; j < FJ; ++j)
            b[j] = *reinterpret_cast<const bf16x8*>(
                Bs + (size_t)(wn * (BN / 2) + j * 16 + r16) * 32 + kq);
#pragma unroll
        for (int i = 0; i < FI; ++i)
#pragma unroll
            for (int j = 0; j < FJ; ++j)
                acc[i][j] = __builtin_amdgcn_mfma_f32_16x16x32_bf16(a[i], b[j], acc[i][j], 0, 0, 0);
        __syncthreads();
    }

    const int crow0 = (lane >> 4) * 4;
    const int ccol  = lane & 15;
#pragma unroll
    for (int i = 0; i < FI; ++i)
#pragma unroll
        for (int j = 0; j < FJ; ++j)
#pragma unroll
            for (int r = 0; r < 4; ++r) {
                size_t row = tileM + wm * (BM / 2) + i * 16 + crow0 + r;
                size_t col = tileN + wn * (BN / 2) + j * 16 + ccol;
                float v = acc[i][j][r];
                if (OUT_BF16)
                    ((__hip_bfloat16*)Cout)[row * N + col] = __float2bfloat16(v);
                else
                    ((float*)Cout)[row * N + col] = v;
            }
}

// One thread per (b,h,t). kv fp32 [Bb*16][2*Cc] (K cols 0..1023, V cols 1024..2047).
// Fixed key set = tokens 0..15 (degenerate top-k), validity slot <= t.
__global__ __launch_bounds__(256)
void attn_kernel(const __hip_bfloat16* __restrict__ q,   // [Bb*Tt][Cc] bf16
                 const float* __restrict__ kv,
                 __hip_bfloat16* __restrict__ attn)       // [Bb*Tt][Cc] bf16
{
    __shared__ float ks[Kk][HD];
    __shared__ float vs[Kk][HD];
    const int bid = blockIdx.x;       // (b*16 + h)*4 + tchunk
    const int bh = bid >> 2;
    const int tchunk = bid & 3;
    const int b = bh >> 4;
    const int h = bh & 15;

    for (int e = threadIdx.x; e < Kk * HD; e += 256) {
        int slot = e >> 6, d = e & 63;
        size_t rowoff = (size_t)(b * Kk + slot) * (2 * Cc);
        ks[slot][d] = kv[rowoff + h * HD + d];
        vs[slot][d] = kv[rowoff + Cc + h * HD + d];
    }
    __syncthreads();

    const int t = tchunk * 256 + threadIdx.x;
    const size_t m = (size_t)b * Tt + t;

    float qf[HD];
    const __hip_bfloat16* qrow = q + m * Cc + (size_t)h * HD;
#pragma unroll
    for (int d = 0; d < HD; d += 8) {
        bf16x8 v = *reinterpret_cast<const bf16x8*>(qrow + d);
#pragma unroll
        for (int j = 0; j < 8; ++j) qf[d + j] = (float)v[j];
    }

    const int nv = min(t, Kk - 1) + 1;
    float logits[Kk];
    float mx = -3.0e38f;
    for (int k = 0; k < Kk; ++k) {
        float s = 0.f;
#pragma unroll
        for (int d = 0; d < HD; ++d) s += qf[d] * ks[k][d];
        s *= 0.125f;
        logits[k] = s;
        if (k < nv) mx = fmaxf(mx, s);
    }
    float w[Kk];
    float sum = 0.f;
    for (int k = 0; k < Kk; ++k) {
        float e = (k < nv) ? __expf(logits[k] - mx) : 0.f;
        w[k] = e;
        sum += e;
    }
    const float inv = 1.f / sum;

    float outv[HD];
#pragma unroll
    for (int d = 0; d < HD; ++d) outv[d] = 0.f;
    for (int k = 0; k < nv; ++k) {
        float wk = w[k] * inv;
#pragma unroll
        for (int d = 0; d < HD; ++d) outv[d] += wk * vs[k][d];
    }

    __hip_bfloat16* orow = attn + m * Cc + (size_t)h * HD;
#pragma unroll
    for (int d = 0; d < HD; d += 8) {
        bf16x8 v;
#pragma unroll
        for (int j = 0; j < 8; ++j) v[j] = f2bf(outv[d + j]);
        *reinterpret_cast<bf16x8*>(orow + d) = v;
    }
}

extern "C" void kernel_launch(void* const* d_in, const int* in_sizes, int n_in,
                              void* d_out, int out_size, void* d_ws, size_t ws_size,
                              hipStream_t stream)
{
    (void)in_sizes; (void)n_in; (void)out_size; (void)ws_size;
    const float* x      = (const float*)d_in[0];
    const float* W_attn = (const float*)d_in[1];
    const float* W_proj = (const float*)d_in[2];
    // d_in[3] = W_rel is dead (confirmed by round-4 pass): top_k values are
    // discarded; only finite score is col 0 -> idx = [0..15] for every (h,t).
    float* out = (float*)d_out;

    char* ws = (char*)d_ws;
    float*          kv_ws   = (float*)ws;                          // 512 KB fp32 [64][2048]
    __hip_bfloat16* xb      = (__hip_bfloat16*)(ws + (512u << 10));            // 8 MB
    __hip_bfloat16* Wab     = (__hip_bfloat16*)(ws + (512u << 10) + (8u << 20));  // 6 MB
    __hip_bfloat16* Wpb     = (__hip_bfloat16*)(ws + (512u << 10) + (14u << 20)); // 2 MB
    __hip_bfloat16* q_ws    = (__hip_bfloat16*)(ws + (512u << 10) + (16u << 20)); // 8 MB
    __hip_bfloat16* attn_ws = (__hip_bfloat16*)(ws + (512u << 10) + (24u << 20)); // 8 MB

    // fp32 -> bf16 conversions (one-time; enables global_load_lds staging).
    cvt_f32_bf16<<<2048, 256, 0, stream>>>(x,      xb,  Bb * Tt * Cc);
    cvt_f32_bf16<<<1536, 256, 0, stream>>>(W_attn, Wab, 3 * Cc * Cc);
    cvt_f32_bf16<<< 512, 256, 0, stream>>>(W_proj, Wpb, Cc * Cc);

    // K/V for tokens 0..15 per batch: M=64 (gathered), N=2048 (Wk|Wv), fp32 out.
    gemm_mfma<64, 64, true, false><<<dim3(2048 / 64, 1), 256, 0, stream>>>(
        xb, Wab + (size_t)Cc * Cc, kv_ws, 64, 2048, Cc);
    // Q: M=4096, N=1024, bf16 out.
    gemm_mfma<128, 64, false, true><<<dim3(1024 / 64, 4096 / 128), 256, 0, stream>>>(
        xb, Wab, q_ws, Bb * Tt, Cc, Cc);
    // Sparse attention (fixed 16 keys, validity slot<=t).
    attn_kernel<<<Bb * 16 * (Tt / 256), 256, 0, stream>>>(q_ws, kv_ws, attn_ws);
    // Output projection -> d_out fp32.
    gemm_mfma<128, 64, false, false><<<dim3(1024 / 64, 4096 / 128), 256, 0, stream>>>(
        attn_ws, Wpb, out, Bb * Tt, Cc, Cc);
}